// Round 7
// baseline (83.729 us; speedup 1.0000x reference)
//
#include <hip/hip_runtime.h>

#define BATCH 131072
#define NS    300
#define H     100
#define BLK   512                 /* 8 waves/block; 2 blocks/CU -> 4 waves/SIMD */
#define EPB   256                 /* elements per block (128 quads x 2) */
#define NQ4   (EPB * NS / 4)      /* 19200 float4 outputs per block */

#define REP25(M) M(0) M(1) M(2) M(3) M(4) M(5) M(6) M(7) M(8) M(9) M(10) M(11) \
  M(12) M(13) M(14) M(15) M(16) M(17) M(18) M(19) M(20) M(21) M(22) M(23) M(24)

__device__ __forceinline__ float qswap1(float x) {   /* quad_perm [1,0,3,2] */
    return __int_as_float(__builtin_amdgcn_mov_dpp(__float_as_int(x), 0xB1, 0xF, 0xF, true));
}
__device__ __forceinline__ float qswap2(float x) {   /* quad_perm [2,3,0,1] */
    return __int_as_float(__builtin_amdgcn_mov_dpp(__float_as_int(x), 0x4E, 0xF, 0xF, true));
}

__global__ __launch_bounds__(BLK, 4)   /* min 4 waves/EU -> VGPR cap 128, no spill at ~95 live */
void lorentz_fused(const float* __restrict__ G,  const float* __restrict__ W1,
                   const float* __restrict__ b1, const float* __restrict__ W2,
                   const float* __restrict__ b2, const float* __restrict__ Ww0,
                   const float* __restrict__ Wwp, const float* __restrict__ Wg,
                   float* __restrict__ out)
{
    /* W2 chunked [j][q][28] (25 used, 3 pad) -> per-(j,q) chunk = 7 aligned float4 */
    __shared__ float4 sW2c4[H * 4 * 7];        /* 44800 B */
    __shared__ float4 sHead4[H * 4];           /*  6400 B: (Ww0,Wwp,Wg,0) per (j,q) */
    __shared__ float4 sP04[EPB], sP14[EPB], sP24[EPB];  /* 12288 B params */
    __shared__ float  sW1[H * 8];              /*  3200 B */
    __shared__ float  sB1[H], sB2[H];          /*   800 B */

    const int tid = threadIdx.x;

    /* ---- stage weights (once per block) ---- */
    {
        float* sW2cF = (float*)sW2c4;
        for (int i = tid; i < H * H; i += BLK) {
            int j = i / 100, k = i - j * 100;
            int q = k / 25, kk = k - q * 25;
            sW2cF[(j * 4 + q) * 28 + kk] = W2[i];
        }
        for (int i = tid; i < H * 8; i += BLK) sW1[i] = W1[i];
        for (int i = tid; i < H; i += BLK) { sB1[i] = b1[i]; sB2[i] = b2[i]; }
        float* sHeadF = (float*)sHead4;
        for (int i = tid; i < H * 4; i += BLK) {
            int j = i >> 2, q = i & 3;
            sHeadF[i * 4 + 0] = Ww0[q * H + j];
            sHeadF[i * 4 + 1] = Wwp[q * H + j];
            sHeadF[i * 4 + 2] = Wg [q * H + j];
            sHeadF[i * 4 + 3] = 0.f;
        }
    }
    __syncthreads();

    const int q  = tid & 3;          /* k-chunk / oscillator owner */
    const int gi = tid >> 2;         /* element pair 0..127 */
    const int e0 = blockIdx.x * EPB + gi * 2;

    /* ---- inputs for both elements ---- */
    const float4* gp = (const float4*)(G + (size_t)e0 * 8);
    const float4 ga0 = gp[0], gb0 = gp[1];
    const float4 ga1 = gp[2], gb1 = gp[3];

    /* ---- layer 1: lane computes h1[q*25 .. q*25+24] for 2 elements ---- */
#define H1DECL(i) float h1a_##i, h1b_##i;
    REP25(H1DECL)
#undef H1DECL
#define L1E(dst, ga, gb)                                                        \
        { float s0 = fmaf(ga.x, ra.x, bb);  float s1 = ga.y * ra.y;             \
          s0 = fmaf(ga.z, ra.z, s0);  s1 = fmaf(ga.w, ra.w, s1);                \
          s0 = fmaf(gb.x, rb.x, s0);  s1 = fmaf(gb.y, rb.y, s1);                \
          s0 = fmaf(gb.z, rb.z, s0);  s1 = fmaf(gb.w, rb.w, s1);                \
          dst = fmaxf(s0 + s1, 0.f); }
#define L1(i) { const float4* r = (const float4*)&sW1[(q * 25 + (i)) * 8];      \
        const float4 ra = r[0], rb = r[1];                                      \
        const float bb = sB1[q * 25 + (i)];                                     \
        L1E(h1a_##i, ga0, gb0)  L1E(h1b_##i, ga1, gb1) }
    REP25(L1)
#undef L1

    /* ---- layer 2 + heads: per j, 25-fma partial dot x2 elements,
       DPP quad butterfly completes each 100-sum, heads accumulate osc q. ---- */
    float aw0a = 0.f, awpa = 0.f, agga = 0.f;
    float aw0b = 0.f, awpb = 0.f, aggb = 0.f;

#pragma unroll 2
    for (int j = 0; j < H; ++j) {
        const int cb = (j * 4 + q) * 7;
        const float4 c0 = sW2c4[cb + 0], c1 = sW2c4[cb + 1], c2 = sW2c4[cb + 2],
                     c3 = sW2c4[cb + 3], c4 = sW2c4[cb + 4], c5 = sW2c4[cb + 5],
                     c6 = sW2c4[cb + 6];
        const float4 hv  = sHead4[j * 4 + q];
        const float  b2j = sB2[j];

        float pa = 0.f, pb = 0.f;
#define CH1(w, i) pa = fmaf(h1a_##i, w, pa); pb = fmaf(h1b_##i, w, pb);
#define CH(t, i0, i1, i2, i3)                                                   \
        CH1(c##t.x, i0) CH1(c##t.y, i1) CH1(c##t.z, i2) CH1(c##t.w, i3)
        CH(0, 0, 1, 2, 3)     CH(1, 4, 5, 6, 7)     CH(2, 8, 9, 10, 11)
        CH(3, 12, 13, 14, 15) CH(4, 16, 17, 18, 19) CH(5, 20, 21, 22, 23)
        CH1(c6.x, 24)
#undef CH
#undef CH1
        float sa = pa + qswap1(pa); sa += qswap2(sa);
        float sb = pb + qswap1(pb); sb += qswap2(sb);
        const float h2a = fmaxf(sa + b2j, 0.f);
        const float h2b = fmaxf(sb + b2j, 0.f);

        aw0a = fmaf(h2a, hv.x, aw0a); awpa = fmaf(h2a, hv.y, awpa); agga = fmaf(h2a, hv.z, agga);
        aw0b = fmaf(h2b, hv.x, aw0b); awpb = fmaf(h2b, hv.y, awpb); aggb = fmaf(h2b, hv.z, aggb);
    }

    /* ---- derived params -> LDS (lane q owns oscillator q of its 2 elements) ---- */
    {
        float* P0 = (float*)sP04; float* P1 = (float*)sP14; float* P2 = (float*)sP24;
#define EMIT(aw, ap, ag, e)                                                     \
        { const float w0 = fmaxf(aw, 0.f), wp = fmaxf(ap, 0.f), gg = fmaxf(ag, 0.f); \
          const int ix = (gi * 2 + (e)) * 4 + q;                                \
          P0[ix] = w0 * w0;  P1[ix] = gg * gg;  P2[ix] = wp * wp * gg; }
        EMIT(aw0a, awpa, agga, 0)
        EMIT(aw0b, awpb, aggb, 1)
#undef EMIT
    }
    __syncthreads();

    /* ---- spectrum: block's contiguous 256*300-float region, float4 stores.
       19200 quads / 512 threads = 37 full iterations + 256-thread tail. ---- */
    float4* out4 = (float4*)out;
    const size_t base4 = (size_t)blockIdx.x * NQ4;

#define SPEC(idx4)                                                              \
    {   const int e  = (idx4) / 75;                                             \
        const int k4 = (idx4) - e * 75;                                         \
        const float4 P0 = sP04[e], P1 = sP14[e], P2 = sP24[e];                  \
        const float kb = (float)(k4 << 2);                                      \
        float4 r; float* rp = (float*)&r;                                       \
        _Pragma("unroll")                                                       \
        for (int i = 0; i < 4; ++i) {                                           \
            const float w   = 0.5f + (kb + (float)i) * 0.015f;                  \
            const float wsq = w * w;                                            \
            const float t0 = P0.x - wsq, t1 = P0.y - wsq,                       \
                        t2 = P0.z - wsq, t3 = P0.w - wsq;                       \
            const float d0 = fmaf(t0, t0, wsq * P1.x);                          \
            const float d1 = fmaf(t1, t1, wsq * P1.y);                          \
            const float d2 = fmaf(t2, t2, wsq * P1.z);                          \
            const float d3 = fmaf(t3, t3, wsq * P1.w);                          \
            const float d01 = d0 * d1, d23 = d2 * d3;                           \
            const float D   = d01 * d23;                                        \
            const float n01 = fmaf(P2.y, d0, P2.x * d1);                        \
            const float n23 = fmaf(P2.w, d2, P2.z * d3);                        \
            const float N   = fmaf(n01, d23, n23 * d01);                        \
            rp[i] = w * (N * __builtin_amdgcn_rcpf(D));                         \
        }                                                                       \
        out4[base4 + (idx4)] = r; }

    for (int it = 0; it < NQ4 / BLK; ++it) {        /* 37 full iterations */
        const int idx4 = it * BLK + tid;
        SPEC(idx4)
    }
    if (tid < NQ4 - (NQ4 / BLK) * BLK) {            /* tail: 256 quads */
        const int idx4 = (NQ4 / BLK) * BLK + tid;
        SPEC(idx4)
    }
#undef SPEC
}

extern "C" void kernel_launch(void* const* d_in, const int* in_sizes, int n_in,
                              void* d_out, int out_size, void* d_ws, size_t ws_size,
                              hipStream_t stream) {
    const float* G   = (const float*)d_in[0];
    const float* W1  = (const float*)d_in[1];
    const float* b1  = (const float*)d_in[2];
    const float* W2  = (const float*)d_in[3];
    const float* b2  = (const float*)d_in[4];
    const float* Ww0 = (const float*)d_in[5];
    const float* Wwp = (const float*)d_in[6];
    const float* Wg  = (const float*)d_in[7];
    float* out = (float*)d_out;

    dim3 grid(BATCH / EPB);   /* 512 blocks */
    dim3 block(BLK);
    lorentz_fused<<<grid, block, 0, stream>>>(G, W1, b1, W2, b2, Ww0, Wwp, Wg, out);
}